// Round 16
// baseline (675.638 us; speedup 1.0000x reference)
//
#include <hip/hip_runtime.h>
#include <hip/hip_fp16.h>
#include <cstddef>

#define NN 50000      // nodes
#define EE 800000     // edges per adjacency
#define KF 500        // NFEAT
#define D1 128        // H2
#define D2 64         // H3
#define D3 64         // H4
#define NC 7          // classes
#define NIDX 5000     // index size
#define NTK 16        // ceil(KF/32) k-tiles for layer-1
#define NB 391        // ceil(NN/128) row-blocks
#define NBKT 196      // ceil(NN/256) row buckets
#define BCHUNK 4096   // edges per chunk
#define NCHUNK 196    // ceil(EE/BCHUNK)
#define BKTCAP 5120   // LDS edge capacity in order4
#define NBLK4 12500   // (NN+3)/4 spmm blocks per slot
#define NCVX (NB*NTK) // 6256 convx blocks

typedef __attribute__((ext_vector_type(8))) _Float16 f16x8;
typedef __attribute__((ext_vector_type(4))) float f32x4;
typedef __attribute__((ext_vector_type(4))) unsigned short u16x4;
typedef __attribute__((ext_vector_type(8))) unsigned short u16x8;

__device__ __forceinline__ void stage1k(const unsigned short* g, unsigned short* l, int lane){
  __builtin_amdgcn_global_load_lds((const __attribute__((address_space(1))) void*)(g + lane*8),
                                   (__attribute__((address_space(3))) void*)l, 16, 0, 0);
}
__device__ __forceinline__ void stage16(const void* g_lane, void* lds_base){
  __builtin_amdgcn_global_load_lds((const __attribute__((address_space(1))) void*)g_lane,
                                   (__attribute__((address_space(3))) void*)lds_base, 16, 0, 0);
}

// ================= gather primitives =================
// mixed-precision FMA: acc += f16(lo/hi of rw) * v   (fp32 accumulate, exact f16 promote)
__device__ __forceinline__ void fmamix2(float& a0, float& a1, unsigned rw, float v){
  asm volatile("v_fma_mix_f32 %0, %2, %3, %0 op_sel:[0,0,0] op_sel_hi:[1,0,0]\n\t"
               "v_fma_mix_f32 %1, %2, %3, %1 op_sel:[1,0,0] op_sel_hi:[1,0,0]"
               : "+v"(a0), "+v"(a1)
               : "v"(rw), "v"(v));
}

template<int H>
__device__ __forceinline__ void gacc(unsigned e, const __half* __restrict__ S, int q, float* acc){
  int c = (int)(e >> 16);
  float v = __half2float(__ushort_as_half((unsigned short)(e & 0xFFFFu)));
  const __half* sp = S + (size_t)c*H + q*(H/16);
  if (H == 128){
    uint4 raw = *reinterpret_cast<const uint4*>(sp);
    fmamix2(acc[0], acc[1], raw.x, v);
    fmamix2(acc[2], acc[3], raw.y, v);
    fmamix2(acc[4], acc[5], raw.z, v);
    fmamix2(acc[6], acc[7], raw.w, v);
  } else {
    uint2 raw = *reinterpret_cast<const uint2*>(sp);
    fmamix2(acc[0], acc[1], raw.x, v);
    fmamix2(acc[2], acc[3], raw.y, v);
  }
}

template<int H>
__device__ __forceinline__ void gather_row(const unsigned* __restrict__ ecvp, int p0, int p1,
                                           const __half* __restrict__ S, int lane, float* acc){
  int g = lane >> 4, q = lane & 15;
  for (int base = p0; base < p1; base += 64){
    int nrem = p1 - base; if (nrem > 64) nrem = 64;
    unsigned pk = (lane < nrem) ? ecvp[base + lane] : 0u;
    int i = 0;
    for (; i + 16 <= nrem; i += 16){
      unsigned e0 = __shfl(pk, i + g);
      unsigned e1 = __shfl(pk, i + 4 + g);
      unsigned e2 = __shfl(pk, i + 8 + g);
      unsigned e3 = __shfl(pk, i + 12 + g);
      gacc<H>(e0, S, q, acc);
      gacc<H>(e1, S, q, acc);
      gacc<H>(e2, S, q, acc);
      gacc<H>(e3, S, q, acc);
    }
    for (; i < nrem; i += 4){
      int idx = i + g;
      unsigned e = __shfl(pk, idx);
      if (idx < nrem) gacc<H>(e, S, q, acc);
    }
  }
}

template<int COLS>
__device__ __forceinline__ void stv(__half* p, float* a){
  #pragma unroll
  for (int j = 0; j < COLS; j += 2)
    *reinterpret_cast<__half2*>(p + j) = __floats2half2_rn(a[j], a[j+1]);
}
template<int COLS>
__device__ __forceinline__ void stv(float* p, float* a){
  #pragma unroll
  for (int j = 0; j < COLS; j += 4)
    *reinterpret_cast<float4*>(p + j) = make_float4(a[j], a[j+1], a[j+2], a[j+3]);
}

// ================= device bodies for fused phase kernels =================
// x -> fragment-tiled fp16 plane
__device__ void convx_dev(int b, const float* __restrict__ A,
                          unsigned short* __restrict__ Xf, int M, int K, char* smem){
  int rb = b / NTK, ks = b % NTK;
  float (*T)[33] = reinterpret_cast<float(*)[33]>(smem);
  int t = threadIdx.x;
  int tr = t >> 3, tk = (t & 7) * 4;
  #pragma unroll
  for (int p = 0; p < 4; ++p){
    int r = tr + p*32;
    int gr = rb*128 + r, gk = ks*32 + tk;
    float4 v = make_float4(0.f,0.f,0.f,0.f);
    if (gr < M && gk + 4 <= K) v = *reinterpret_cast<const float4*>(&A[(size_t)gr*K + gk]);
    T[r][tk] = v.x; T[r][tk+1] = v.y; T[r][tk+2] = v.z; T[r][tk+3] = v.w;
  }
  __syncthreads();
  size_t tb = (size_t)b * 4096;
  unsigned short hh[16];
  #pragma unroll
  for (int i = 0; i < 16; ++i){
    int e = t*16 + i;
    int f = e >> 9, rem = e & 511, l = rem >> 3, kr = rem & 7;
    int row = f*16 + (l & 15), k = ((l >> 4) << 3) + kr;
    hh[i] = __half_as_ushort(__float2half(T[row][k]));
  }
  *reinterpret_cast<u16x8*>(&Xf[tb + t*16])     = *reinterpret_cast<u16x8*>(&hh[0]);
  *reinterpret_cast<u16x8*>(&Xf[tb + t*16 + 8]) = *reinterpret_cast<u16x8*>(&hh[8]);
}

// big W -> fragment-tiled fp16-split planes
__device__ void wtcf_dev(int which, int ks,
                         const float* __restrict__ W0, const float* __restrict__ W1,
                         const float* __restrict__ W2,
                         unsigned short* H0, unsigned short* L0,
                         unsigned short* H1, unsigned short* L1,
                         unsigned short* H2, unsigned short* L2, int K){
  const float* W = (which==0)?W0:(which==1)?W1:W2;
  unsigned short* H = (which==0)?H0:(which==1)?H1:H2;
  unsigned short* L = (which==0)?L0:(which==1)?L1:L2;
  int t = threadIdx.x;
  size_t tb = (size_t)ks * 4096;
  unsigned short hh[16], ll[16];
  #pragma unroll
  for (int i = 0; i < 16; ++i){
    int e = t*16 + i;
    int f = e >> 9, rem = e & 511, l = rem >> 3, kr = rem & 7;
    int col = f*16 + (l & 15), k = ks*32 + ((l >> 4) << 3) + kr;
    float v = (k < K) ? W[(size_t)k*D1 + col] : 0.f;
    __half hv = __float2half(v);
    float r = v - __half2float(hv);
    __half lv = __float2half(r);
    hh[i] = __half_as_ushort(hv);
    ll[i] = __half_as_ushort(lv);
  }
  *reinterpret_cast<u16x8*>(&H[tb + t*16])     = *reinterpret_cast<u16x8*>(&hh[0]);
  *reinterpret_cast<u16x8*>(&H[tb + t*16 + 8]) = *reinterpret_cast<u16x8*>(&hh[8]);
  *reinterpret_cast<u16x8*>(&L[tb + t*16])     = *reinterpret_cast<u16x8*>(&ll[0]);
  *reinterpret_cast<u16x8*>(&L[tb + t*16 + 8]) = *reinterpret_cast<u16x8*>(&ll[8]);
}

__device__ void wtcs_dev(int which, int ks,
                         const float* __restrict__ W0, const float* __restrict__ W1,
                         const float* __restrict__ W2,
                         unsigned short* H0, unsigned short* L0,
                         unsigned short* H1, unsigned short* L1,
                         unsigned short* H2, unsigned short* L2, int K){
  const float* W = (which==0)?W0:(which==1)?W1:W2;
  unsigned short* H = (which==0)?H0:(which==1)?H1:H2;
  unsigned short* L = (which==0)?L0:(which==1)?L1:L2;
  int t = threadIdx.x;
  size_t tb = (size_t)ks * 2048;
  unsigned short hh[8], ll[8];
  #pragma unroll
  for (int i = 0; i < 8; ++i){
    int e = t*8 + i;
    int f = e >> 9, rem = e & 511, l = rem >> 3, kr = rem & 7;
    int col = f*16 + (l & 15), k = ks*32 + ((l >> 4) << 3) + kr;
    float v = (k < K) ? W[(size_t)k*64 + col] : 0.f;
    __half hv = __float2half(v);
    float r = v - __half2float(hv);
    __half lv = __float2half(r);
    hh[i] = __half_as_ushort(hv);
    ll[i] = __half_as_ushort(lv);
  }
  *reinterpret_cast<u16x8*>(&H[tb + t*8]) = *reinterpret_cast<u16x8*>(&hh[0]);
  *reinterpret_cast<u16x8*>(&L[tb + t*8]) = *reinterpret_cast<u16x8*>(&ll[0]);
}

__device__ void bchist_dev(int adj, int ch,
                           const int* __restrict__ r0, const int* __restrict__ r1,
                           const int* __restrict__ r2, const int* __restrict__ r3,
                           int* __restrict__ bcntm, char* smem){
  const int* r = (adj==0)?r0:(adj==1)?r1:(adj==2)?r2:r3;
  int* cnt = (int*)smem;
  int tid = threadIdx.x;
  cnt[tid] = 0;
  __syncthreads();
  int e0 = ch*BCHUNK;
  #pragma unroll
  for (int j = 0; j < BCHUNK/256; ++j){
    int i = e0 + j*256 + tid;
    if (i < EE) atomicAdd(&cnt[r[i] >> 8], 1);
  }
  __syncthreads();
  if (tid < NBKT) bcntm[((size_t)(adj*NCHUNK) + ch)*NBKT + tid] = cnt[tid];
}

__device__ void bin4_dev(int adj, int ch,
    const int* __restrict__ r0, const int* __restrict__ c0, const float* __restrict__ v0,
    const int* __restrict__ r1, const int* __restrict__ c1, const float* __restrict__ v1,
    const int* __restrict__ r2, const int* __restrict__ c2, const float* __restrict__ v2,
    const int* __restrict__ r3, const int* __restrict__ c3, const float* __restrict__ v3,
    const int* __restrict__ bbase, const int* __restrict__ blkoff,
    int2* __restrict__ eint4, char* smem){
  const int* r = (adj==0)?r0:(adj==1)?r1:(adj==2)?r2:r3;
  const int* c = (adj==0)?c0:(adj==1)?c1:(adj==2)?c2:c3;
  const float* v = (adj==0)?v0:(adj==1)?v1:(adj==2)?v2:v3;
  int2* eint = eint4 + (size_t)adj*EE;
  int* base = (int*)smem;
  int* cur  = base + 256;
  int tid = threadIdx.x;
  cur[tid] = 0;
  if (tid < NBKT)
    base[tid] = bbase[adj*NBKT + tid] + blkoff[((size_t)(adj*NCHUNK) + ch)*NBKT + tid];
  __syncthreads();
  int e0 = ch*BCHUNK;
  #pragma unroll
  for (int j = 0; j < BCHUNK/256; ++j){
    int i = e0 + j*256 + tid;
    if (i < EE){
      int rr = r[i];
      int b = rr >> 8;
      int p = base[b] + atomicAdd(&cur[b], 1);
      eint[p] = make_int2((rr << 16) | c[i], __float_as_int(v[i]));
    }
  }
}

// layer-1 fused 3x GEMM: A fp16 plane, B fp16-split; 2 MFMAs per pair
__device__ void gemm3f_dev(int b,
    const unsigned short* __restrict__ Xf,
    const unsigned short* __restrict__ B0h, const unsigned short* __restrict__ B0l,
    const unsigned short* __restrict__ B1h, const unsigned short* __restrict__ B1l,
    const unsigned short* __restrict__ B2h, const unsigned short* __restrict__ B2l,
    __half* __restrict__ C0, __half* __restrict__ C1, __half* __restrict__ C2,
    int M, char* smem){
  unsigned short* Af = (unsigned short*)smem;
  unsigned short* Bh = Af + 4096;
  unsigned short* Bl = Bh + 4096;
  int which = b % 3;
  int rb    = b / 3;
  const unsigned short* BhP = (which==0)?B0h:(which==1)?B1h:B2h;
  const unsigned short* BlP = (which==0)?B0l:(which==1)?B1l:B2l;
  __half* C = (which==0)?C0:(which==1)?C1:C2;

  int tid = threadIdx.x;
  int lane = tid & 63, wid = tid >> 6;
  int wr = wid >> 1, wc = wid & 1;

  f32x4 acc[4][4];
  #pragma unroll
  for (int i = 0; i < 4; ++i)
    #pragma unroll
    for (int j = 0; j < 4; ++j) acc[i][j] = (f32x4){0.f,0.f,0.f,0.f};

  for (int ks = 0; ks < NTK; ++ks){
    size_t atb = ((size_t)(rb*NTK + ks)) * 4096;
    size_t btb = (size_t)ks * 4096;
    if (wid == 0){
      #pragma unroll
      for (int c = 0; c < 4; ++c) stage1k(Xf + atb + c*512, Af + c*512, lane);
    } else if (wid == 1){
      #pragma unroll
      for (int c = 4; c < 8; ++c) stage1k(Xf + atb + c*512, Af + c*512, lane);
    } else if (wid == 2){
      #pragma unroll
      for (int c = 0; c < 8; ++c) stage1k(BhP + btb + c*512, Bh + c*512, lane);
    } else {
      #pragma unroll
      for (int c = 0; c < 8; ++c) stage1k(BlP + btb + c*512, Bl + c*512, lane);
    }
    __syncthreads();

    f16x8 af[4], bh[4], bl[4];
    int fo = lane * 8;
    #pragma unroll
    for (int mi = 0; mi < 4; ++mi)
      af[mi] = *reinterpret_cast<const f16x8*>(&Af[(wr*4 + mi)*512 + fo]);
    #pragma unroll
    for (int ni = 0; ni < 4; ++ni){
      bh[ni] = *reinterpret_cast<const f16x8*>(&Bh[(wc*4 + ni)*512 + fo]);
      bl[ni] = *reinterpret_cast<const f16x8*>(&Bl[(wc*4 + ni)*512 + fo]);
    }
    #pragma unroll
    for (int mi = 0; mi < 4; ++mi)
      #pragma unroll
      for (int ni = 0; ni < 4; ++ni){
        acc[mi][ni] = __builtin_amdgcn_mfma_f32_16x16x32_f16(af[mi], bh[ni], acc[mi][ni], 0, 0, 0);
        acc[mi][ni] = __builtin_amdgcn_mfma_f32_16x16x32_f16(af[mi], bl[ni], acc[mi][ni], 0, 0, 0);
      }
    __syncthreads();
  }
  #pragma unroll
  for (int mi = 0; mi < 4; ++mi){
    int rowb = rb*128 + wr*64 + mi*16 + (lane >> 4)*4;
    #pragma unroll
    for (int ni = 0; ni < 4; ++ni){
      int col = wc*64 + ni*16 + (lane & 15);
      #pragma unroll
      for (int i = 0; i < 4; ++i){
        int r = rowb + i;
        if (r < M) C[(size_t)r*128 + col] = __float2half(acc[mi][ni][i]);
      }
    }
  }
}

// ================= fused phase kernels =================
__global__ __launch_bounds__(256) void megaA_kernel(
    const float* x, unsigned short* Xf,
    const float* w1, const float* w4, const float* w10,
    unsigned short* B1H, unsigned short* B1L, unsigned short* B4H, unsigned short* B4L,
    unsigned short* B10H, unsigned short* B10L,
    const float* w2, const float* w5, const float* w11,
    unsigned short* V2H, unsigned short* V2L, unsigned short* V5H, unsigned short* V5L,
    unsigned short* V11H, unsigned short* V11L,
    const float* w3, const float* w6, const float* w12,
    unsigned short* V3H, unsigned short* V3L, unsigned short* V6H, unsigned short* V6L,
    unsigned short* V12H, unsigned short* V12L,
    const int* r0, const int* r1, const int* r2, const int* r3,
    int* bcntm){
  __shared__ __align__(16) char smem[16896];
  int b = blockIdx.x;
  if (b < NCVX){
    convx_dev(b, x, Xf, NN, KF, smem);
  } else if (b < NCVX + 48){
    int i = b - NCVX;
    wtcf_dev(i / NTK, i % NTK, w1, w4, w10, B1H,B1L, B4H,B4L, B10H,B10L, KF);
  } else if (b < NCVX + 48 + 12){
    int i = b - NCVX - 48;
    wtcs_dev(i >> 2, i & 3, w2, w5, w11, V2H,V2L, V5H,V5L, V11H,V11L, D1);
  } else if (b < NCVX + 48 + 18){
    int i = b - NCVX - 60;
    wtcs_dev(i >> 1, i & 1, w3, w6, w12, V3H,V3L, V6H,V6L, V12H,V12L, D2);
  } else {
    int i = b - NCVX - 66;
    bchist_dev(i / NCHUNK, i % NCHUNK, r0, r1, r2, r3, bcntm, smem);
  }
}

__global__ __launch_bounds__(256) void megaC_kernel(
    const unsigned short* Xf,
    const unsigned short* B1H, const unsigned short* B1L,
    const unsigned short* B4H, const unsigned short* B4L,
    const unsigned short* B10H, const unsigned short* B10L,
    __half* S1, __half* S4, __half* S10,
    const int* r0, const int* c0, const float* v0,
    const int* r1, const int* c1, const float* v1,
    const int* r2, const int* c2, const float* v2,
    const int* r3, const int* c3, const float* v3,
    const int* bbase, const int* blkoff, int2* eint4){
  __shared__ __align__(16) char smem[24576];
  int b = blockIdx.x;
  if (b < 3*NB){
    gemm3f_dev(b, Xf, B1H,B1L, B4H,B4L, B10H,B10L, S1, S4, S10, NN, smem);
  } else {
    int i = b - 3*NB;
    bin4_dev(i / NCHUNK, i % NCHUNK, r0,c0,v0, r1,c1,v1, r2,c2,v2, r3,c3,v3,
             bbase, blkoff, eint4, smem);
  }
}

// ================= CSR scans =================
__global__ __launch_bounds__(256) void bscan_kernel(const int* __restrict__ bcntm,
                                                    int* __restrict__ blkoff,
                                                    int* __restrict__ btot){
  int adj = blockIdx.y, b = blockIdx.x;
  __shared__ int sbuf[256];
  int c = threadIdx.x;
  int v = (c < NCHUNK) ? bcntm[((size_t)(adj*NCHUNK) + c)*NBKT + b] : 0;
  sbuf[c] = v;
  __syncthreads();
  for (int off = 1; off < 256; off <<= 1){
    int t = (c >= off) ? sbuf[c - off] : 0;
    __syncthreads();
    sbuf[c] += t;
    __syncthreads();
  }
  if (c < NCHUNK) blkoff[((size_t)(adj*NCHUNK) + c)*NBKT + b] = sbuf[c] - v;
  if (c == 255) btot[adj*NBKT + b] = sbuf[255];
}
__global__ __launch_bounds__(256) void bbase_kernel(const int* __restrict__ btot,
                                                    int* __restrict__ bbase){
  int adj = blockIdx.x;
  __shared__ int sbuf[256];
  int b = threadIdx.x;
  int v = (b < NBKT) ? btot[adj*NBKT + b] : 0;
  sbuf[b] = v;
  __syncthreads();
  for (int off = 1; off < 256; off <<= 1){
    int t = (b >= off) ? sbuf[b - off] : 0;
    __syncthreads();
    sbuf[b] += t;
    __syncthreads();
  }
  if (b < NBKT) bbase[adj*NBKT + b] = sbuf[b] - v;
}

// ================= order4 =================
__global__ __launch_bounds__(256) void order4_kernel(const int* __restrict__ bbase4,
                                                     const int* __restrict__ btot4,
                                                     const int2* __restrict__ eint4,
                                                     unsigned* __restrict__ ecvp4,
                                                     int* __restrict__ rowp4){
  int adj = blockIdx.y, b = blockIdx.x;
  int base = bbase4[adj*NBKT + b];
  int cnt  = btot4[adj*NBKT + b];
  const int2* eint = eint4 + (size_t)adj*EE;
  unsigned* ecvp = ecvp4 + (size_t)adj*EE;
  int* rowp = rowp4 + (size_t)adj*(NN+1);
  int rlo = b << 8;
  int tid = threadIdx.x;
  __shared__ unsigned rawk[BKTCAP];
  __shared__ unsigned short rawv[BKTCAP];
  __shared__ unsigned dst[BKTCAP];
  __shared__ int rcnt[256], sbuf[256], wro[257], rcur[256];
  rcnt[tid] = 0; rcur[tid] = 0;
  __syncthreads();
  if (cnt <= BKTCAP){
    for (int e = tid; e < cnt; e += 256){
      int2 pk = eint[base + e];
      rawk[e] = (unsigned)pk.x;
      rawv[e] = __half_as_ushort(__float2half(__int_as_float(pk.y)));
      atomicAdd(&rcnt[(((unsigned)pk.x) >> 16) - rlo], 1);
    }
    __syncthreads();
    sbuf[tid] = rcnt[tid];
    __syncthreads();
    for (int off = 1; off < 256; off <<= 1){
      int t = (tid >= off) ? sbuf[tid - off] : 0;
      __syncthreads();
      sbuf[tid] += t;
      __syncthreads();
    }
    wro[tid] = sbuf[tid] - rcnt[tid];
    if (tid == 255) wro[256] = sbuf[255];
    __syncthreads();
    int r = rlo + tid;
    if (r < NN) rowp[r] = base + wro[tid];
    if (b == NBKT-1 && tid == 0) rowp[NN] = EE;
    for (int e = tid; e < cnt; e += 256){
      int rr = (rawk[e] >> 16) - rlo;
      int pos = wro[rr] + atomicAdd(&rcur[rr], 1);
      dst[pos] = (rawk[e] << 16) | (unsigned)rawv[e];
    }
    __syncthreads();
    {
      int s0 = wro[tid], s1 = wro[tid+1];
      for (int i = s0 + 1; i < s1; ++i){
        unsigned key = dst[i];
        int j = i - 1;
        while (j >= s0 && dst[j] > key){ dst[j+1] = dst[j]; --j; }
        dst[j+1] = key;
      }
    }
    __syncthreads();
    for (int e = tid; e < cnt; e += 256) ecvp[base + e] = dst[e];
  } else {
    for (int e = tid; e < cnt; e += 256){
      int2 pk = eint[base + e];
      atomicAdd(&rcnt[(((unsigned)pk.x) >> 16) - rlo], 1);
    }
    __syncthreads();
    sbuf[tid] = rcnt[tid];
    __syncthreads();
    for (int off = 1; off < 256; off <<= 1){
      int t = (tid >= off) ? sbuf[tid - off] : 0;
      __syncthreads();
      sbuf[tid] += t;
      __syncthreads();
    }
    wro[tid] = sbuf[tid] - rcnt[tid];
    if (tid == 255) wro[256] = sbuf[255];
    __syncthreads();
    int r = rlo + tid;
    if (r < NN) rowp[r] = base + wro[tid];
    if (b == NBKT-1 && tid == 0) rowp[NN] = EE;
    for (int e = tid; e < cnt; e += 256){
      int2 pk = eint[base + e];
      int rr = (((unsigned)pk.x) >> 16) - rlo;
      unsigned hv = (unsigned)__half_as_ushort(__float2half(__int_as_float(pk.y)));
      int pos = wro[rr] + atomicAdd(&rcur[rr], 1);
      ecvp[base + pos] = (((unsigned)pk.x) << 16) | hv;
    }
  }
}

// ================= 4-slot f16 MFMA GEMM =================
__global__ __launch_bounds__(256) void mfma4f_kernel(
    const __half* __restrict__ A0, const __half* __restrict__ A1,
    const __half* __restrict__ A2, const __half* __restrict__ A3,
    const unsigned short* __restrict__ Bh0, const unsigned short* __restrict__ Bh1,
    const unsigned short* __restrict__ Bh2, const unsigned short* __restrict__ Bh3,
    const unsigned short* __restrict__ Bl0, const unsigned short* __restrict__ Bl1,
    const unsigned short* __restrict__ Bl2, const unsigned short* __restrict__ Bl3,
    __half* __restrict__ C0, __half* __restrict__ C1,
    __half* __restrict__ C2, __half* __restrict__ C3,
    int M, int K){
  __shared__ __align__(16) unsigned short As[4096];
  __shared__ __align__(16) unsigned short Bhs[2048], Bls[2048];
  int slot = blockIdx.y;
  const __half* A = (slot==0)?A0:(slot==1)?A1:(slot==2)?A2:A3;
  const unsigned short* Bh = (slot==0)?Bh0:(slot==1)?Bh1:(slot==2)?Bh2:Bh3;
  const unsigned short* Bl = (slot==0)?Bl0:(slot==1)?Bl1:(slot==2)?Bl2:Bl3;
  __half* C = (slot==0)?C0:(slot==1)?C1:(slot==2)?C2:C3;

  int tid = threadIdx.x;
  int lane = tid & 63, wid = tid >> 6;
  int wr = wid >> 1, wc = wid & 1;
  int row0 = blockIdx.x*128;
  int frow = lane & 15, fko = (lane >> 4)*8;

  f32x4 acc[4][2];
  #pragma unroll
  for (int i = 0; i < 4; ++i){ acc[i][0] = (f32x4){0,0,0,0}; acc[i][1] = (f32x4){0,0,0,0}; }

  for (int k0 = 0; k0 < K; k0 += 32){
    if (wid < 2){
      #pragma unroll
      for (int s = 0; s < 4; ++s){
        int f = wid*4 + s;
        const __half* g = A + (size_t)(row0 + f*16 + frow)*K + (k0 + fko);
        stage16(g, As + f*512);
      }
    } else {
      const unsigned short* src = (wid == 2) ? Bh : Bl;
      unsigned short* dst = (wid == 2) ? Bhs : Bls;
      size_t tb = (size_t)(k0 >> 5) * 2048;
      #pragma unroll
      for (int s = 0; s < 4; ++s) stage1k(src + tb + s*512, dst + s*512, lane);
    }
    __syncthreads();
    f16x8 a[4], bh[2], bl[2];
    #pragma unroll
    for (int mi = 0; mi < 4; ++mi)
      a[mi] = *reinterpret_cast<const f16x8*>(&As[(wr*4 + mi)*512 + lane*8]);
    #pragma unroll
    for (int ni = 0; ni < 2; ++ni){
      bh[ni] = *reinterpret_cast<const f16x8*>(&Bhs[(wc*2 + ni)*512 + lane*8]);
      bl[ni] = *reinterpret_cast<const f16x8*>(&Bls[(wc*2 + ni)*512 + lane*8]);
    }
    #pragma unroll
    for (int mi = 0; mi < 4; ++mi)
      #pragma unroll
      for (int ni = 0; ni < 2; ++ni){
        acc[mi][ni] = __builtin_amdgcn_mfma_f32_16x16x32_f16(a[mi], bh[ni], acc[mi][ni], 0, 0, 0);
        acc[mi][ni] = __builtin_amdgcn_mfma_f32_16x16x32_f16(a[mi], bl[ni], acc[mi][ni], 0, 0, 0);
      }
    __syncthreads();
  }
  #pragma unroll
  for (int mi = 0; mi < 4; ++mi){
    int rowb = row0 + wr*64 + mi*16 + (lane >> 4)*4;
    #pragma unroll
    for (int ni = 0; ni < 2; ++ni){
      int col = wc*32 + ni*16 + (lane & 15);
      #pragma unroll
      for (int i = 0; i < 4; ++i){
        int r = rowb + i;
        if (r < M) C[(size_t)r*64 + col] = __float2half(acc[mi][ni][i]);
      }
    }
  }
}

// ================= slot-major gather SpMM (OT = __half or float) =================
template<int H, int RELU, typename OT>
__global__ __launch_bounds__(256) void spmm4_kernel(
    const int* __restrict__ rowp4, const unsigned* __restrict__ ecvp4,
    const __half* __restrict__ S0, const __half* __restrict__ S1,
    const __half* __restrict__ S2, const __half* __restrict__ S3,
    const float* __restrict__ B0, const float* __restrict__ B1,
    const float* __restrict__ B2, const float* __restrict__ B3,
    OT* __restrict__ O0, OT* __restrict__ O1, OT* __restrict__ O2, OT* __restrict__ O3){
  constexpr int COLS = H / 16;
  int slot = blockIdx.x / NBLK4;
  int bid  = blockIdx.x - slot*NBLK4;
  const int* row_ptr = rowp4 + (size_t)slot*(NN+1);
  const unsigned* ecvp = ecvp4 + (size_t)slot*EE;
  const __half* S   = (slot==0)?S0:(slot==1)?S1:(slot==2)?S2:S3;
  const float* bias = (slot==0)?B0:(slot==1)?B1:(slot==2)?B2:B3;
  OT* out           = (slot==0)?O0:(slot==1)?O1:(slot==2)?O2:O3;

  int row = bid*4 + (threadIdx.x >> 6);
  int lane = threadIdx.x & 63;
  if (row >= NN) return;
  int q = lane & 15;
  int p0 = row_ptr[row], p1 = row_ptr[row+1];
  float acc[COLS];
  #pragma unroll
  for (int j = 0; j < COLS; ++j) acc[j] = 0.f;
  gather_row<H>(ecvp, p0, p1, S, lane, acc);
  #pragma unroll
  for (int j = 0; j < COLS; ++j){
    acc[j] += __shfl_xor(acc[j], 16);
    acc[j] += __shfl_xor(acc[j], 32);
  }
  if (lane < 16){
    #pragma unroll
    for (int j = 0; j < COLS; j += 4){
      float4 bz = *reinterpret_cast<const float4*>(bias + q*COLS + j);
      acc[j] += bz.x; acc[j+1] += bz.y; acc[j+2] += bz.z; acc[j+3] += bz.w;
    }
    #pragma unroll
    for (int j = 0; j < COLS; ++j)
      if (RELU) acc[j] = fmaxf(acc[j], 0.f);
    stv<COLS>(out + (size_t)row*H + q*COLS, acc);
  }
}

// ================= 5-slot dense (4 branch heads + sim) =================
__global__ __launch_bounds__(256) void dense75_kernel(
    const float* __restrict__ A0, const float* __restrict__ A1,
    const float* __restrict__ A2, const float* __restrict__ A3,
    const float* __restrict__ W0, const float* __restrict__ W1,
    const float* __restrict__ W2, const float* __restrict__ W3,
    const float* __restrict__ bb0, const float* __restrict__ bb1,
    const float* __restrict__ bb2, const float* __restrict__ bb3,
    float* __restrict__ o0, float* __restrict__ o1,
    float* __restrict__ o2, float* __restrict__ o3,
    const float* __restrict__ sw, const float* __restrict__ sb,
    float* __restrict__ simout){
  int slot = blockIdx.y;
  __shared__ float Ws[128*NC];
  __shared__ float bs[NC];
  if (slot < 4){
    const float* A = (slot==0)?A0:(slot==1)?A1:(slot==2)?A2:A3;
    const float* W = (slot==0)?W0:(slot==1)?W1:(slot==2)?W2:W3;
    const float* bb= (slot==0)?bb0:(slot==1)?bb1:(slot==2)?bb2:bb3;
    float* o       = (slot==0)?o0:(slot==1)?o1:(slot==2)?o2:o3;
    for (int i = threadIdx.x; i < 64*NC; i += 256) Ws[i] = W[i];
    if (threadIdx.x < NC) bs[threadIdx.x] = bb[threadIdx.x];
    __syncthreads();
    int row = blockIdx.x*256 + threadIdx.x;
    if (row >= NN) return;
    float acc[NC];
    #pragma unroll
    for (int n = 0; n < NC; ++n) acc[n] = bs[n];
    const float* a = A + (size_t)row*64;
    #pragma unroll 4
    for (int k = 0; k < 64; ++k){
      float av = fmaxf(a[k], 0.f);
      #pragma unroll
      for (int n = 0; n < NC; ++n) acc[n] += av*Ws[k*NC + n];
    }
    #pragma unroll
    for (int n = 0; n < NC; ++n) o[(size_t)row*NC + n] = acc[n];
  } else {
    for (int i = threadIdx.x; i < 128*NC; i += 256) Ws[i] = sw[i];
    if (threadIdx.x < NC) bs[threadIdx.x] = sb[threadIdx.x];
    __syncthreads();
    int row = blockIdx.x*256 + threadIdx.x;
    if (row >= NN) return;
    float acc[NC];
    #pragma unroll
    for (int n = 0; n < NC; ++n) acc[n] = bs[n];
    const float* a1 = A1 + (size_t)row*64;   // X2
    const float* a2 = A2 + (size_t)row*64;   // X3
    #pragma unroll 4
    for (int k = 0; k < 64; ++k){
      float av = a1[k];
      #pragma unroll
      for (int n = 0; n < NC; ++n) acc[n] += av*Ws[k*NC + n];
    }
    #pragma unroll 4
    for (int k = 0; k < 64; ++k){
      float av = a2[k];
      #pragma unroll
      for (int n = 0; n < NC; ++n) acc[n] += av*Ws[(64 + k)*NC + n];
    }
    #pragma unroll
    for (int n = 0; n < NC; ++n) simout[(size_t)row*NC + n] = acc[n];
  }
}

// ================= alpha / axpy =================
__global__ __launch_bounds__(1024) void alpha_kernel(const float* __restrict__ base, const float* __restrict__ gate,
                                                     const float* __restrict__ y, const int* __restrict__ index,
                                                     float* __restrict__ alpha_out){
  __shared__ float r1[1024], r2[1024];
  int tid = threadIdx.x;
  float s1 = 0.f, sall = 0.f;
  for (int i = tid; i < NIDX*NC; i += 1024){
    int ii = i / NC, n = i - ii*NC;
    int r = index[ii];
    float yv = y[(size_t)r*NC + n];
    float b = base[(size_t)r*NC + n];
    float g = gate[(size_t)r*NC + n];
    float te = expf(-b*yv);
    sall += te;
    if (g*yv >= 0.f) s1 += te;
  }
  r1[tid] = s1; r2[tid] = sall;
  __syncthreads();
  for (int off = 512; off > 0; off >>= 1){
    if (tid < off){ r1[tid] += r1[tid+off]; r2[tid] += r2[tid+off]; }
    __syncthreads();
  }
  if (tid == 0){
    float s2 = r2[0] - r1[0];
    alpha_out[0] = 0.5f*logf(s2/r1[0]);
  }
}

__global__ void axpy_kernel(const float* __restrict__ a, const float* __restrict__ b,
                            const float* __restrict__ alpha, float* __restrict__ out, int n){
  int i = blockIdx.x*blockDim.x + threadIdx.x;
  if (i < n) out[i] = a[i] + alpha[0]*b[i];
}

// ---------------- host ----------------
extern "C" void kernel_launch(void* const* d_in, const int* in_sizes, int n_in,
                              void* d_out, int out_size, void* d_ws, size_t ws_size,
                              hipStream_t stream){
  const float* x     = (const float*)d_in[0];
  const float* y     = (const float*)d_in[1];
  const int*   index = (const int*)d_in[2];
  const int*   a1r = (const int*)d_in[3];  const int* a1c = (const int*)d_in[4];  const float* a1v = (const float*)d_in[5];
  const int*   a3r = (const int*)d_in[9];  const int* a3c = (const int*)d_in[10]; const float* a3v = (const float*)d_in[11];
  const int*   a4r = (const int*)d_in[12]; const int* a4c = (const int*)d_in[13]; const float* a4v = (const float*)d_in[14];
  const int*   a5r = (const int*)d_in[15]; const int* a5c = (const int*)d_in[16]; const float* a5v = (const float*)d_in[17];
  const float* w1  = (const float*)d_in[18]; const float* b1  = (const float*)d_in[19];
  const float* w2  = (const float*)d_in[20]; const float* b2  = (const float*)d_in[21];
  const float* w3  = (const float*)d_in[22]; const float* b3  = (const float*)d_in[23];
  const float* w4  = (const float*)d_in[24]; const float* b4  = (const float*)d_in[25];
  const float* w5  = (const float*)d_in[26]; const float* b5  = (const float*)d_in[27];
  const float* w6  = (const float*)d_in[28]; const float* b6  = (const float*)d_in[29];
  const float* w10 = (const float*)d_in[30]; const float* b10 = (const float*)d_in[31];
  const float* w11 = (const float*)d_in[32]; const float* b11 = (const float*)d_in[33];
  const float* w12 = (const float*)d_in[34]; const float* b12 = (const float*)d_in[35];
  const float* d1w = (const float*)d_in[36]; const float* d1b = (const float*)d_in[37];
  const float* d2w = (const float*)d_in[38]; const float* d2b = (const float*)d_in[39];
  const float* d3w = (const float*)d_in[40]; const float* d3b = (const float*)d_in[41];
  const float* d4w = (const float*)d_in[42]; const float* d4b = (const float*)d_in[43];
  const float* sw  = (const float*)d_in[44]; const float* sb  = (const float*)d_in[45];
  float* out = (float*)d_out;
  (void)n_in; (void)in_sizes; (void)out_size; (void)ws_size;

  float* OUT_X2D = out;
  float* OUT_X3D = out + (size_t)NN*NC;
  float* OUT_P2  = out + (size_t)2*NN*NC;

  char* p = (char*)d_ws;
  auto carve = [&](size_t bytes) -> char* {
    char* q = p;
    p += (bytes + 255) & ~size_t(255);
    return q;
  };

  // Region A (102.5MB), time-shared: phase A: Xf (51.2MB)  phase B: H1_4 | SB_4 | H2_4
  const size_t XH_BYTES = (size_t)NB*NTK*4096*2;     // 51,249,152
  char* regionA = carve(2*XH_BYTES);
  unsigned short* Xf = (unsigned short*)regionA;
  __half* H1_4  = (__half*)regionA;                                  // 51.2MB
  __half* SB_4  = (__half*)(regionA + XH_BYTES);                     // 25.6MB
  __half* H2_4  = (__half*)(regionA + XH_BYTES + (size_t)4*NN*D2*2); // 25.6MB

  int2*  EINT4 = (int2*)carve((size_t)4*EE*8);
  __half* S1  = (__half*)carve((size_t)NN*D1*2);
  __half* S4  = (__half*)carve((size_t)NN*D1*2);
  __half* S10 = (__half*)carve((size_t)NN*D1*2);
  float* X1R  = (float*)carve((size_t)NN*D3*4);
  float* X2   = (float*)carve((size_t)NN*D3*4);
  float* X3   = (float*)carve((size_t)NN*D3*4);
  float* X4R  = (float*)carve((size_t)NN*D3*4);
  float* X1D  = (float*)carve((size_t)NN*NC*4);
  float* X4D  = (float*)carve((size_t)NN*NC*4);
  float* SIM  = (float*)carve((size_t)NN*NC*4);
  float* ALPHA= (float*)carve(256);
  int*   ROWP4 = (int*)carve((size_t)4*(NN+1)*4);
  int*   BCNTM = (int*)carve((size_t)4*NCHUNK*NBKT*4);
  int*   BLKOFF= (int*)carve((size_t)4*NCHUNK*NBKT*4);
  int*   BTOT  = (int*)carve((size_t)4*NBKT*4);
  int*   BBASE = (int*)carve((size_t)4*NBKT*4);
  const size_t BTE = (size_t)NTK*4096;
  unsigned short* B1H = (unsigned short*)carve(BTE*2); unsigned short* B1L = (unsigned short*)carve(BTE*2);
  unsigned short* B4H = (unsigned short*)carve(BTE*2); unsigned short* B4L = (unsigned short*)carve(BTE*2);
  unsigned short* B10H= (unsigned short*)carve(BTE*2); unsigned short* B10L= (unsigned short*)carve(BTE*2);
  unsigned short* V2H  = (unsigned short*)carve(4*2048*2); unsigned short* V2L  = (unsigned short*)carve(4*2048*2);
  unsigned short* V5H  = (unsigned short*)carve(4*2048*2); unsigned short* V5L  = (unsigned short*)carve(4*2048*2);
  unsigned short* V11H = (unsigned short*)carve(4*2048*2); unsigned short* V11L = (unsigned short*)carve(4*2048*2);
  unsigned short* V3H  = (unsigned short*)carve(2*2048*2); unsigned short* V3L  = (unsigned short*)carve(2*2048*2);
  unsigned short* V6H  = (unsigned short*)carve(2*2048*2); unsigned short* V6L  = (unsigned short*)carve(2*2048*2);
  unsigned short* V12H = (unsigned short*)carve(2*2048*2); unsigned short* V12L = (unsigned short*)carve(2*2048*2);
  unsigned* ECVP4 = (unsigned*)carve((size_t)4*EE*4);

  __half* H1s[4]; __half* SBs[4]; __half* H2s[4];
  for (int s = 0; s < 4; ++s){
    H1s[s] = H1_4 + (size_t)s*NN*D1;
    SBs[s] = SB_4 + (size_t)s*NN*D2;
    H2s[s] = H2_4 + (size_t)s*NN*D2;
  }

  // ---- phase A: convx(fp16) ∥ weight prep ∥ bchist (slots: 0=a5, 1=a4, 2=a3, 3=a1) ----
  megaA_kernel<<<NCVX + 48 + 18 + 4*NCHUNK, 256, 0, stream>>>(
      x, Xf,
      w1, w4, w10, B1H,B1L, B4H,B4L, B10H,B10L,
      w2, w5, w11, V2H,V2L, V5H,V5L, V11H,V11L,
      w3, w6, w12, V3H,V3L, V6H,V6L, V12H,V12L,
      a5r, a4r, a3r, a1r, BCNTM);
  // ---- phase B: scans ----
  bscan_kernel<<<dim3(NBKT,4), 256, 0, stream>>>(BCNTM, BLKOFF, BTOT);
  bbase_kernel<<<4, 256, 0, stream>>>(BTOT, BBASE);
  // ---- phase C: gemm3f(fp16 A) ∥ bin4 ----
  megaC_kernel<<<3*NB + 4*NCHUNK, 256, 0, stream>>>(
      Xf, B1H,B1L, B4H,B4L, B10H,B10L, S1, S4, S10,
      a5r,a5c,a5v, a4r,a4c,a4v, a3r,a3c,a3v, a1r,a1c,a1v,
      BBASE, BLKOFF, EINT4);
  // ---- phase D: order4 (writes ROWP4); Xf dead after megaC -> regionA reused ----
  order4_kernel<<<dim3(NBKT,4), 256, 0, stream>>>(BBASE, BTOT, EINT4, ECVP4, ROWP4);

  // ---- branch stages ----
  spmm4_kernel<128,1,__half><<<4*NBLK4, 256, 0, stream>>>(
      ROWP4, ECVP4, S1,S4,S4,S10, b1,b4,b4,b10, H1s[0],H1s[1],H1s[2],H1s[3]);
  mfma4f_kernel<<<dim3(NB,4), 256, 0, stream>>>(
      H1s[0],H1s[1],H1s[2],H1s[3], V2H,V5H,V5H,V11H, V2L,V5L,V5L,V11L,
      SBs[0],SBs[1],SBs[2],SBs[3], NN, D1);
  spmm4_kernel<64,1,__half><<<4*NBLK4, 256, 0, stream>>>(
      ROWP4, ECVP4, SBs[0],SBs[1],SBs[2],SBs[3], b2,b5,b5,b11, H2s[0],H2s[1],H2s[2],H2s[3]);
  mfma4f_kernel<<<dim3(NB,4), 256, 0, stream>>>(
      H2s[0],H2s[1],H2s[2],H2s[3], V3H,V6H,V6H,V12H, V3L,V6L,V6L,V12L,
      SBs[0],SBs[1],SBs[2],SBs[3], NN, D2);
  spmm4_kernel<64,0,float><<<4*NBLK4, 256, 0, stream>>>(
      ROWP4, ECVP4, SBs[0],SBs[1],SBs[2],SBs[3], b3,b6,b6,b12, X1R,X2,X3,X4R);
  dense75_kernel<<<dim3((NN+255)/256,5), 256, 0, stream>>>(
      X1R,X2,X3,X4R, d1w,d2w,d3w,d4w, d1b,d2b,d3b,d4b,
      X1D, OUT_X2D, OUT_X3D, X4D, sw, sb, SIM);

  // ---- adaboost epilogue ----
  alpha_kernel<<<1, 1024, 0, stream>>>(X4D, SIM, y, index, ALPHA);
  axpy_kernel<<<((NN*NC)+255)/256, 256, 0, stream>>>(X4D, SIM, ALPHA, OUT_P2, NN*NC);
  alpha_kernel<<<1, 1024, 0, stream>>>(OUT_P2, X1D, y, index, ALPHA+1);
  axpy_kernel<<<((NN*NC)+255)/256, 256, 0, stream>>>(OUT_P2, X1D, ALPHA+1, OUT_P2, NN*NC);
}

// Round 17
// 647.855 us; speedup vs baseline: 1.0429x; 1.0429x over previous
//
#include <hip/hip_runtime.h>
#include <hip/hip_fp16.h>
#include <cstddef>

#define NN 50000      // nodes
#define EE 800000     // edges per adjacency
#define KF 500        // NFEAT
#define D1 128        // H2
#define D2 64         // H3
#define D3 64         // H4
#define NC 7          // classes
#define NIDX 5000     // index size
#define NTK 16        // ceil(KF/32) k-tiles for layer-1
#define NB 391        // ceil(NN/128) row-blocks
#define NBKT 196      // ceil(NN/256) row buckets
#define BCHUNK 4096   // edges per chunk
#define NCHUNK 196    // ceil(EE/BCHUNK)
#define BKTCAP 5120   // LDS edge capacity in order4
#define NBLK4 12500   // (NN+3)/4 spmm blocks per slot
#define NCVX (NB*NTK) // 6256 convx blocks

typedef __attribute__((ext_vector_type(8))) _Float16 f16x8;
typedef __attribute__((ext_vector_type(4))) float f32x4;
typedef __attribute__((ext_vector_type(4))) unsigned short u16x4;
typedef __attribute__((ext_vector_type(8))) unsigned short u16x8;

__device__ __forceinline__ void stage1k(const unsigned short* g, unsigned short* l, int lane){
  __builtin_amdgcn_global_load_lds((const __attribute__((address_space(1))) void*)(g + lane*8),
                                   (__attribute__((address_space(3))) void*)l, 16, 0, 0);
}
__device__ __forceinline__ void stage16(const void* g_lane, void* lds_base){
  __builtin_amdgcn_global_load_lds((const __attribute__((address_space(1))) void*)g_lane,
                                   (__attribute__((address_space(3))) void*)lds_base, 16, 0, 0);
}

// ================= gather primitives =================
template<int H>
__device__ __forceinline__ void gacc(unsigned e, const __half* __restrict__ S, int q, float* acc){
  int c = (int)(e >> 16);
  float v = __half2float(__ushort_as_half((unsigned short)(e & 0xFFFFu)));
  const __half* sp = S + (size_t)c*H + q*(H/16);
  if (H == 128){
    uint4 raw = *reinterpret_cast<const uint4*>(sp);
    float2 f0 = __half22float2(*reinterpret_cast<__half2*>(&raw.x));
    float2 f1 = __half22float2(*reinterpret_cast<__half2*>(&raw.y));
    float2 f2 = __half22float2(*reinterpret_cast<__half2*>(&raw.z));
    float2 f3 = __half22float2(*reinterpret_cast<__half2*>(&raw.w));
    acc[0] += v*f0.x; acc[1] += v*f0.y; acc[2] += v*f1.x; acc[3] += v*f1.y;
    acc[4] += v*f2.x; acc[5] += v*f2.y; acc[6] += v*f3.x; acc[7] += v*f3.y;
  } else {
    uint2 raw = *reinterpret_cast<const uint2*>(sp);
    float2 f0 = __half22float2(*reinterpret_cast<__half2*>(&raw.x));
    float2 f1 = __half22float2(*reinterpret_cast<__half2*>(&raw.y));
    acc[0] += v*f0.x; acc[1] += v*f0.y; acc[2] += v*f1.x; acc[3] += v*f1.y;
  }
}

template<int H>
__device__ __forceinline__ void gather_row(const unsigned* __restrict__ ecvp, int p0, int p1,
                                           const __half* __restrict__ S, int lane, float* acc){
  int g = lane >> 4, q = lane & 15;
  for (int base = p0; base < p1; base += 64){
    int nrem = p1 - base; if (nrem > 64) nrem = 64;
    unsigned pk = (lane < nrem) ? ecvp[base + lane] : 0u;
    int i = 0;
    for (; i + 16 <= nrem; i += 16){
      unsigned e0 = __shfl(pk, i + g);
      unsigned e1 = __shfl(pk, i + 4 + g);
      unsigned e2 = __shfl(pk, i + 8 + g);
      unsigned e3 = __shfl(pk, i + 12 + g);
      gacc<H>(e0, S, q, acc);
      gacc<H>(e1, S, q, acc);
      gacc<H>(e2, S, q, acc);
      gacc<H>(e3, S, q, acc);
    }
    for (; i < nrem; i += 4){
      int idx = i + g;
      unsigned e = __shfl(pk, idx);
      if (idx < nrem) gacc<H>(e, S, q, acc);
    }
  }
}

template<int COLS>
__device__ __forceinline__ void stv(__half* p, float* a){
  #pragma unroll
  for (int j = 0; j < COLS; j += 2)
    *reinterpret_cast<__half2*>(p + j) = __floats2half2_rn(a[j], a[j+1]);
}
template<int COLS>
__device__ __forceinline__ void stv(float* p, float* a){
  #pragma unroll
  for (int j = 0; j < COLS; j += 4)
    *reinterpret_cast<float4*>(p + j) = make_float4(a[j], a[j+1], a[j+2], a[j+3]);
}

// ================= device bodies for fused phase kernels =================
// x -> fragment-tiled fp16 plane
__device__ void convx_dev(int b, const float* __restrict__ A,
                          unsigned short* __restrict__ Xf, int M, int K, char* smem){
  int rb = b / NTK, ks = b % NTK;
  float (*T)[33] = reinterpret_cast<float(*)[33]>(smem);
  int t = threadIdx.x;
  int tr = t >> 3, tk = (t & 7) * 4;
  #pragma unroll
  for (int p = 0; p < 4; ++p){
    int r = tr + p*32;
    int gr = rb*128 + r, gk = ks*32 + tk;
    float4 v = make_float4(0.f,0.f,0.f,0.f);
    if (gr < M && gk + 4 <= K) v = *reinterpret_cast<const float4*>(&A[(size_t)gr*K + gk]);
    T[r][tk] = v.x; T[r][tk+1] = v.y; T[r][tk+2] = v.z; T[r][tk+3] = v.w;
  }
  __syncthreads();
  size_t tb = (size_t)b * 4096;
  unsigned short hh[16];
  #pragma unroll
  for (int i = 0; i < 16; ++i){
    int e = t*16 + i;
    int f = e >> 9, rem = e & 511, l = rem >> 3, kr = rem & 7;
    int row = f*16 + (l & 15), k = ((l >> 4) << 3) + kr;
    hh[i] = __half_as_ushort(__float2half(T[row][k]));
  }
  *reinterpret_cast<u16x8*>(&Xf[tb + t*16])     = *reinterpret_cast<u16x8*>(&hh[0]);
  *reinterpret_cast<u16x8*>(&Xf[tb + t*16 + 8]) = *reinterpret_cast<u16x8*>(&hh[8]);
}

// big W -> fragment-tiled fp16-split planes
__device__ void wtcf_dev(int which, int ks,
                         const float* __restrict__ W0, const float* __restrict__ W1,
                         const float* __restrict__ W2,
                         unsigned short* H0, unsigned short* L0,
                         unsigned short* H1, unsigned short* L1,
                         unsigned short* H2, unsigned short* L2, int K){
  const float* W = (which==0)?W0:(which==1)?W1:W2;
  unsigned short* H = (which==0)?H0:(which==1)?H1:H2;
  unsigned short* L = (which==0)?L0:(which==1)?L1:L2;
  int t = threadIdx.x;
  size_t tb = (size_t)ks * 4096;
  unsigned short hh[16], ll[16];
  #pragma unroll
  for (int i = 0; i < 16; ++i){
    int e = t*16 + i;
    int f = e >> 9, rem = e & 511, l = rem >> 3, kr = rem & 7;
    int col = f*16 + (l & 15), k = ks*32 + ((l >> 4) << 3) + kr;
    float v = (k < K) ? W[(size_t)k*D1 + col] : 0.f;
    __half hv = __float2half(v);
    float r = v - __half2float(hv);
    __half lv = __float2half(r);
    hh[i] = __half_as_ushort(hv);
    ll[i] = __half_as_ushort(lv);
  }
  *reinterpret_cast<u16x8*>(&H[tb + t*16])     = *reinterpret_cast<u16x8*>(&hh[0]);
  *reinterpret_cast<u16x8*>(&H[tb + t*16 + 8]) = *reinterpret_cast<u16x8*>(&hh[8]);
  *reinterpret_cast<u16x8*>(&L[tb + t*16])     = *reinterpret_cast<u16x8*>(&ll[0]);
  *reinterpret_cast<u16x8*>(&L[tb + t*16 + 8]) = *reinterpret_cast<u16x8*>(&ll[8]);
}

__device__ void wtcs_dev(int which, int ks,
                         const float* __restrict__ W0, const float* __restrict__ W1,
                         const float* __restrict__ W2,
                         unsigned short* H0, unsigned short* L0,
                         unsigned short* H1, unsigned short* L1,
                         unsigned short* H2, unsigned short* L2, int K){
  const float* W = (which==0)?W0:(which==1)?W1:W2;
  unsigned short* H = (which==0)?H0:(which==1)?H1:H2;
  unsigned short* L = (which==0)?L0:(which==1)?L1:L2;
  int t = threadIdx.x;
  size_t tb = (size_t)ks * 2048;
  unsigned short hh[8], ll[8];
  #pragma unroll
  for (int i = 0; i < 8; ++i){
    int e = t*8 + i;
    int f = e >> 9, rem = e & 511, l = rem >> 3, kr = rem & 7;
    int col = f*16 + (l & 15), k = ks*32 + ((l >> 4) << 3) + kr;
    float v = (k < K) ? W[(size_t)k*64 + col] : 0.f;
    __half hv = __float2half(v);
    float r = v - __half2float(hv);
    __half lv = __float2half(r);
    hh[i] = __half_as_ushort(hv);
    ll[i] = __half_as_ushort(lv);
  }
  *reinterpret_cast<u16x8*>(&H[tb + t*8]) = *reinterpret_cast<u16x8*>(&hh[0]);
  *reinterpret_cast<u16x8*>(&L[tb + t*8]) = *reinterpret_cast<u16x8*>(&ll[0]);
}

__device__ void bchist_dev(int adj, int ch,
                           const int* __restrict__ r0, const int* __restrict__ r1,
                           const int* __restrict__ r2, const int* __restrict__ r3,
                           int* __restrict__ bcntm, char* smem){
  const int* r = (adj==0)?r0:(adj==1)?r1:(adj==2)?r2:r3;
  int* cnt = (int*)smem;
  int tid = threadIdx.x;
  cnt[tid] = 0;
  __syncthreads();
  int e0 = ch*BCHUNK;
  #pragma unroll
  for (int j = 0; j < BCHUNK/256; ++j){
    int i = e0 + j*256 + tid;
    if (i < EE) atomicAdd(&cnt[r[i] >> 8], 1);
  }
  __syncthreads();
  if (tid < NBKT) bcntm[((size_t)(adj*NCHUNK) + ch)*NBKT + tid] = cnt[tid];
}

__device__ void bin4_dev(int adj, int ch,
    const int* __restrict__ r0, const int* __restrict__ c0, const float* __restrict__ v0,
    const int* __restrict__ r1, const int* __restrict__ c1, const float* __restrict__ v1,
    const int* __restrict__ r2, const int* __restrict__ c2, const float* __restrict__ v2,
    const int* __restrict__ r3, const int* __restrict__ c3, const float* __restrict__ v3,
    const int* __restrict__ bbase, const int* __restrict__ blkoff,
    int2* __restrict__ eint4, char* smem){
  const int* r = (adj==0)?r0:(adj==1)?r1:(adj==2)?r2:r3;
  const int* c = (adj==0)?c0:(adj==1)?c1:(adj==2)?c2:c3;
  const float* v = (adj==0)?v0:(adj==1)?v1:(adj==2)?v2:v3;
  int2* eint = eint4 + (size_t)adj*EE;
  int* base = (int*)smem;
  int* cur  = base + 256;
  int tid = threadIdx.x;
  cur[tid] = 0;
  if (tid < NBKT)
    base[tid] = bbase[adj*NBKT + tid] + blkoff[((size_t)(adj*NCHUNK) + ch)*NBKT + tid];
  __syncthreads();
  int e0 = ch*BCHUNK;
  #pragma unroll
  for (int j = 0; j < BCHUNK/256; ++j){
    int i = e0 + j*256 + tid;
    if (i < EE){
      int rr = r[i];
      int b = rr >> 8;
      int p = base[b] + atomicAdd(&cur[b], 1);
      eint[p] = make_int2((rr << 16) | c[i], __float_as_int(v[i]));
    }
  }
}

// layer-1 fused 3x GEMM: A fp16 plane, B fp16-split; 2 MFMAs per pair
__device__ void gemm3f_dev(int b,
    const unsigned short* __restrict__ Xf,
    const unsigned short* __restrict__ B0h, const unsigned short* __restrict__ B0l,
    const unsigned short* __restrict__ B1h, const unsigned short* __restrict__ B1l,
    const unsigned short* __restrict__ B2h, const unsigned short* __restrict__ B2l,
    __half* __restrict__ C0, __half* __restrict__ C1, __half* __restrict__ C2,
    int M, char* smem){
  unsigned short* Af = (unsigned short*)smem;
  unsigned short* Bh = Af + 4096;
  unsigned short* Bl = Bh + 4096;
  int which = b % 3;
  int rb    = b / 3;
  const unsigned short* BhP = (which==0)?B0h:(which==1)?B1h:B2h;
  const unsigned short* BlP = (which==0)?B0l:(which==1)?B1l:B2l;
  __half* C = (which==0)?C0:(which==1)?C1:C2;

  int tid = threadIdx.x;
  int lane = tid & 63, wid = tid >> 6;
  int wr = wid >> 1, wc = wid & 1;

  f32x4 acc[4][4];
  #pragma unroll
  for (int i = 0; i < 4; ++i)
    #pragma unroll
    for (int j = 0; j < 4; ++j) acc[i][j] = (f32x4){0.f,0.f,0.f,0.f};

  for (int ks = 0; ks < NTK; ++ks){
    size_t atb = ((size_t)(rb*NTK + ks)) * 4096;
    size_t btb = (size_t)ks * 4096;
    if (wid == 0){
      #pragma unroll
      for (int c = 0; c < 4; ++c) stage1k(Xf + atb + c*512, Af + c*512, lane);
    } else if (wid == 1){
      #pragma unroll
      for (int c = 4; c < 8; ++c) stage1k(Xf + atb + c*512, Af + c*512, lane);
    } else if (wid == 2){
      #pragma unroll
      for (int c = 0; c < 8; ++c) stage1k(BhP + btb + c*512, Bh + c*512, lane);
    } else {
      #pragma unroll
      for (int c = 0; c < 8; ++c) stage1k(BlP + btb + c*512, Bl + c*512, lane);
    }
    __syncthreads();

    f16x8 af[4], bh[4], bl[4];
    int fo = lane * 8;
    #pragma unroll
    for (int mi = 0; mi < 4; ++mi)
      af[mi] = *reinterpret_cast<const f16x8*>(&Af[(wr*4 + mi)*512 + fo]);
    #pragma unroll
    for (int ni = 0; ni < 4; ++ni){
      bh[ni] = *reinterpret_cast<const f16x8*>(&Bh[(wc*4 + ni)*512 + fo]);
      bl[ni] = *reinterpret_cast<const f16x8*>(&Bl[(wc*4 + ni)*512 + fo]);
    }
    #pragma unroll
    for (int mi = 0; mi < 4; ++mi)
      #pragma unroll
      for (int ni = 0; ni < 4; ++ni){
        acc[mi][ni] = __builtin_amdgcn_mfma_f32_16x16x32_f16(af[mi], bh[ni], acc[mi][ni], 0, 0, 0);
        acc[mi][ni] = __builtin_amdgcn_mfma_f32_16x16x32_f16(af[mi], bl[ni], acc[mi][ni], 0, 0, 0);
      }
    __syncthreads();
  }
  #pragma unroll
  for (int mi = 0; mi < 4; ++mi){
    int rowb = rb*128 + wr*64 + mi*16 + (lane >> 4)*4;
    #pragma unroll
    for (int ni = 0; ni < 4; ++ni){
      int col = wc*64 + ni*16 + (lane & 15);
      #pragma unroll
      for (int i = 0; i < 4; ++i){
        int r = rowb + i;
        if (r < M) C[(size_t)r*128 + col] = __float2half(acc[mi][ni][i]);
      }
    }
  }
}

// ================= fused phase kernels =================
__global__ __launch_bounds__(256) void megaA_kernel(
    const float* x, unsigned short* Xf,
    const float* w1, const float* w4, const float* w10,
    unsigned short* B1H, unsigned short* B1L, unsigned short* B4H, unsigned short* B4L,
    unsigned short* B10H, unsigned short* B10L,
    const float* w2, const float* w5, const float* w11,
    unsigned short* V2H, unsigned short* V2L, unsigned short* V5H, unsigned short* V5L,
    unsigned short* V11H, unsigned short* V11L,
    const float* w3, const float* w6, const float* w12,
    unsigned short* V3H, unsigned short* V3L, unsigned short* V6H, unsigned short* V6L,
    unsigned short* V12H, unsigned short* V12L,
    const int* r0, const int* r1, const int* r2, const int* r3,
    int* bcntm){
  __shared__ __align__(16) char smem[16896];
  int b = blockIdx.x;
  if (b < NCVX){
    convx_dev(b, x, Xf, NN, KF, smem);
  } else if (b < NCVX + 48){
    int i = b - NCVX;
    wtcf_dev(i / NTK, i % NTK, w1, w4, w10, B1H,B1L, B4H,B4L, B10H,B10L, KF);
  } else if (b < NCVX + 48 + 12){
    int i = b - NCVX - 48;
    wtcs_dev(i >> 2, i & 3, w2, w5, w11, V2H,V2L, V5H,V5L, V11H,V11L, D1);
  } else if (b < NCVX + 48 + 18){
    int i = b - NCVX - 60;
    wtcs_dev(i >> 1, i & 1, w3, w6, w12, V3H,V3L, V6H,V6L, V12H,V12L, D2);
  } else {
    int i = b - NCVX - 66;
    bchist_dev(i / NCHUNK, i % NCHUNK, r0, r1, r2, r3, bcntm, smem);
  }
}

__global__ __launch_bounds__(256) void megaC_kernel(
    const unsigned short* Xf,
    const unsigned short* B1H, const unsigned short* B1L,
    const unsigned short* B4H, const unsigned short* B4L,
    const unsigned short* B10H, const unsigned short* B10L,
    __half* S1, __half* S4, __half* S10,
    const int* r0, const int* c0, const float* v0,
    const int* r1, const int* c1, const float* v1,
    const int* r2, const int* c2, const float* v2,
    const int* r3, const int* c3, const float* v3,
    const int* bbase, const int* blkoff, int2* eint4){
  __shared__ __align__(16) char smem[24576];
  int b = blockIdx.x;
  if (b < 3*NB){
    gemm3f_dev(b, Xf, B1H,B1L, B4H,B4L, B10H,B10L, S1, S4, S10, NN, smem);
  } else {
    int i = b - 3*NB;
    bin4_dev(i / NCHUNK, i % NCHUNK, r0,c0,v0, r1,c1,v1, r2,c2,v2, r3,c3,v3,
             bbase, blkoff, eint4, smem);
  }
}

// ================= CSR scans =================
__global__ __launch_bounds__(256) void bscan_kernel(const int* __restrict__ bcntm,
                                                    int* __restrict__ blkoff,
                                                    int* __restrict__ btot){
  int adj = blockIdx.y, b = blockIdx.x;
  __shared__ int sbuf[256];
  int c = threadIdx.x;
  int v = (c < NCHUNK) ? bcntm[((size_t)(adj*NCHUNK) + c)*NBKT + b] : 0;
  sbuf[c] = v;
  __syncthreads();
  for (int off = 1; off < 256; off <<= 1){
    int t = (c >= off) ? sbuf[c - off] : 0;
    __syncthreads();
    sbuf[c] += t;
    __syncthreads();
  }
  if (c < NCHUNK) blkoff[((size_t)(adj*NCHUNK) + c)*NBKT + b] = sbuf[c] - v;
  if (c == 255) btot[adj*NBKT + b] = sbuf[255];
}
__global__ __launch_bounds__(256) void bbase_kernel(const int* __restrict__ btot,
                                                    int* __restrict__ bbase){
  int adj = blockIdx.x;
  __shared__ int sbuf[256];
  int b = threadIdx.x;
  int v = (b < NBKT) ? btot[adj*NBKT + b] : 0;
  sbuf[b] = v;
  __syncthreads();
  for (int off = 1; off < 256; off <<= 1){
    int t = (b >= off) ? sbuf[b - off] : 0;
    __syncthreads();
    sbuf[b] += t;
    __syncthreads();
  }
  if (b < NBKT) bbase[adj*NBKT + b] = sbuf[b] - v;
}

// ================= order4 =================
__global__ __launch_bounds__(256) void order4_kernel(const int* __restrict__ bbase4,
                                                     const int* __restrict__ btot4,
                                                     const int2* __restrict__ eint4,
                                                     unsigned* __restrict__ ecvp4,
                                                     int* __restrict__ rowp4){
  int adj = blockIdx.y, b = blockIdx.x;
  int base = bbase4[adj*NBKT + b];
  int cnt  = btot4[adj*NBKT + b];
  const int2* eint = eint4 + (size_t)adj*EE;
  unsigned* ecvp = ecvp4 + (size_t)adj*EE;
  int* rowp = rowp4 + (size_t)adj*(NN+1);
  int rlo = b << 8;
  int tid = threadIdx.x;
  __shared__ unsigned rawk[BKTCAP];
  __shared__ unsigned short rawv[BKTCAP];
  __shared__ unsigned dst[BKTCAP];
  __shared__ int rcnt[256], sbuf[256], wro[257], rcur[256];
  rcnt[tid] = 0; rcur[tid] = 0;
  __syncthreads();
  if (cnt <= BKTCAP){
    for (int e = tid; e < cnt; e += 256){
      int2 pk = eint[base + e];
      rawk[e] = (unsigned)pk.x;
      rawv[e] = __half_as_ushort(__float2half(__int_as_float(pk.y)));
      atomicAdd(&rcnt[(((unsigned)pk.x) >> 16) - rlo], 1);
    }
    __syncthreads();
    sbuf[tid] = rcnt[tid];
    __syncthreads();
    for (int off = 1; off < 256; off <<= 1){
      int t = (tid >= off) ? sbuf[tid - off] : 0;
      __syncthreads();
      sbuf[tid] += t;
      __syncthreads();
    }
    wro[tid] = sbuf[tid] - rcnt[tid];
    if (tid == 255) wro[256] = sbuf[255];
    __syncthreads();
    int r = rlo + tid;
    if (r < NN) rowp[r] = base + wro[tid];
    if (b == NBKT-1 && tid == 0) rowp[NN] = EE;
    for (int e = tid; e < cnt; e += 256){
      int rr = (rawk[e] >> 16) - rlo;
      int pos = wro[rr] + atomicAdd(&rcur[rr], 1);
      dst[pos] = (rawk[e] << 16) | (unsigned)rawv[e];
    }
    __syncthreads();
    {
      int s0 = wro[tid], s1 = wro[tid+1];
      for (int i = s0 + 1; i < s1; ++i){
        unsigned key = dst[i];
        int j = i - 1;
        while (j >= s0 && dst[j] > key){ dst[j+1] = dst[j]; --j; }
        dst[j+1] = key;
      }
    }
    __syncthreads();
    for (int e = tid; e < cnt; e += 256) ecvp[base + e] = dst[e];
  } else {
    for (int e = tid; e < cnt; e += 256){
      int2 pk = eint[base + e];
      atomicAdd(&rcnt[(((unsigned)pk.x) >> 16) - rlo], 1);
    }
    __syncthreads();
    sbuf[tid] = rcnt[tid];
    __syncthreads();
    for (int off = 1; off < 256; off <<= 1){
      int t = (tid >= off) ? sbuf[tid - off] : 0;
      __syncthreads();
      sbuf[tid] += t;
      __syncthreads();
    }
    wro[tid] = sbuf[tid] - rcnt[tid];
    if (tid == 255) wro[256] = sbuf[255];
    __syncthreads();
    int r = rlo + tid;
    if (r < NN) rowp[r] = base + wro[tid];
    if (b == NBKT-1 && tid == 0) rowp[NN] = EE;
    for (int e = tid; e < cnt; e += 256){
      int2 pk = eint[base + e];
      int rr = (((unsigned)pk.x) >> 16) - rlo;
      unsigned hv = (unsigned)__half_as_ushort(__float2half(__int_as_float(pk.y)));
      int pos = wro[rr] + atomicAdd(&rcur[rr], 1);
      ecvp[base + pos] = (((unsigned)pk.x) << 16) | hv;
    }
  }
}

// ================= 4-slot f16 MFMA GEMM =================
__global__ __launch_bounds__(256) void mfma4f_kernel(
    const __half* __restrict__ A0, const __half* __restrict__ A1,
    const __half* __restrict__ A2, const __half* __restrict__ A3,
    const unsigned short* __restrict__ Bh0, const unsigned short* __restrict__ Bh1,
    const unsigned short* __restrict__ Bh2, const unsigned short* __restrict__ Bh3,
    const unsigned short* __restrict__ Bl0, const unsigned short* __restrict__ Bl1,
    const unsigned short* __restrict__ Bl2, const unsigned short* __restrict__ Bl3,
    __half* __restrict__ C0, __half* __restrict__ C1,
    __half* __restrict__ C2, __half* __restrict__ C3,
    int M, int K){
  __shared__ __align__(16) unsigned short As[4096];
  __shared__ __align__(16) unsigned short Bhs[2048], Bls[2048];
  int slot = blockIdx.y;
  const __half* A = (slot==0)?A0:(slot==1)?A1:(slot==2)?A2:A3;
  const unsigned short* Bh = (slot==0)?Bh0:(slot==1)?Bh1:(slot==2)?Bh2:Bh3;
  const unsigned short* Bl = (slot==0)?Bl0:(slot==1)?Bl1:(slot==2)?Bl2:Bl3;
  __half* C = (slot==0)?C0:(slot==1)?C1:(slot==2)?C2:C3;

  int tid = threadIdx.x;
  int lane = tid & 63, wid = tid >> 6;
  int wr = wid >> 1, wc = wid & 1;
  int row0 = blockIdx.x*128;
  int frow = lane & 15, fko = (lane >> 4)*8;

  f32x4 acc[4][2];
  #pragma unroll
  for (int i = 0; i < 4; ++i){ acc[i][0] = (f32x4){0,0,0,0}; acc[i][1] = (f32x4){0,0,0,0}; }

  for (int k0 = 0; k0 < K; k0 += 32){
    if (wid < 2){
      #pragma unroll
      for (int s = 0; s < 4; ++s){
        int f = wid*4 + s;
        const __half* g = A + (size_t)(row0 + f*16 + frow)*K + (k0 + fko);
        stage16(g, As + f*512);
      }
    } else {
      const unsigned short* src = (wid == 2) ? Bh : Bl;
      unsigned short* dst = (wid == 2) ? Bhs : Bls;
      size_t tb = (size_t)(k0 >> 5) * 2048;
      #pragma unroll
      for (int s = 0; s < 4; ++s) stage1k(src + tb + s*512, dst + s*512, lane);
    }
    __syncthreads();
    f16x8 a[4], bh[2], bl[2];
    #pragma unroll
    for (int mi = 0; mi < 4; ++mi)
      a[mi] = *reinterpret_cast<const f16x8*>(&As[(wr*4 + mi)*512 + lane*8]);
    #pragma unroll
    for (int ni = 0; ni < 2; ++ni){
      bh[ni] = *reinterpret_cast<const f16x8*>(&Bhs[(wc*2 + ni)*512 + lane*8]);
      bl[ni] = *reinterpret_cast<const f16x8*>(&Bls[(wc*2 + ni)*512 + lane*8]);
    }
    #pragma unroll
    for (int mi = 0; mi < 4; ++mi)
      #pragma unroll
      for (int ni = 0; ni < 2; ++ni){
        acc[mi][ni] = __builtin_amdgcn_mfma_f32_16x16x32_f16(a[mi], bh[ni], acc[mi][ni], 0, 0, 0);
        acc[mi][ni] = __builtin_amdgcn_mfma_f32_16x16x32_f16(a[mi], bl[ni], acc[mi][ni], 0, 0, 0);
      }
    __syncthreads();
  }
  #pragma unroll
  for (int mi = 0; mi < 4; ++mi){
    int rowb = row0 + wr*64 + mi*16 + (lane >> 4)*4;
    #pragma unroll
    for (int ni = 0; ni < 2; ++ni){
      int col = wc*32 + ni*16 + (lane & 15);
      #pragma unroll
      for (int i = 0; i < 4; ++i){
        int r = rowb + i;
        if (r < M) C[(size_t)r*64 + col] = __float2half(acc[mi][ni][i]);
      }
    }
  }
}

// ================= slot-major gather SpMM (OT = __half or float) =================
template<int H, int RELU, typename OT>
__global__ __launch_bounds__(256) void spmm4_kernel(
    const int* __restrict__ rowp4, const unsigned* __restrict__ ecvp4,
    const __half* __restrict__ S0, const __half* __restrict__ S1,
    const __half* __restrict__ S2, const __half* __restrict__ S3,
    const float* __restrict__ B0, const float* __restrict__ B1,
    const float* __restrict__ B2, const float* __restrict__ B3,
    OT* __restrict__ O0, OT* __restrict__ O1, OT* __restrict__ O2, OT* __restrict__ O3){
  constexpr int COLS = H / 16;
  int slot = blockIdx.x / NBLK4;
  int bid  = blockIdx.x - slot*NBLK4;
  const int* row_ptr = rowp4 + (size_t)slot*(NN+1);
  const unsigned* ecvp = ecvp4 + (size_t)slot*EE;
  const __half* S   = (slot==0)?S0:(slot==1)?S1:(slot==2)?S2:S3;
  const float* bias = (slot==0)?B0:(slot==1)?B1:(slot==2)?B2:B3;
  OT* out           = (slot==0)?O0:(slot==1)?O1:(slot==2)?O2:O3;

  int row = bid*4 + (threadIdx.x >> 6);
  int lane = threadIdx.x & 63;
  if (row >= NN) return;
  int q = lane & 15;
  int p0 = row_ptr[row], p1 = row_ptr[row+1];
  float acc[COLS];
  #pragma unroll
  for (int j = 0; j < COLS; ++j) acc[j] = 0.f;
  gather_row<H>(ecvp, p0, p1, S, lane, acc);
  #pragma unroll
  for (int j = 0; j < COLS; ++j){
    acc[j] += __shfl_xor(acc[j], 16);
    acc[j] += __shfl_xor(acc[j], 32);
  }
  if (lane < 16){
    #pragma unroll
    for (int j = 0; j < COLS; j += 4){
      float4 bz = *reinterpret_cast<const float4*>(bias + q*COLS + j);
      acc[j] += bz.x; acc[j+1] += bz.y; acc[j+2] += bz.z; acc[j+3] += bz.w;
    }
    #pragma unroll
    for (int j = 0; j < COLS; ++j)
      if (RELU) acc[j] = fmaxf(acc[j], 0.f);
    stv<COLS>(out + (size_t)row*H + q*COLS, acc);
  }
}

// ================= 5-slot dense (4 branch heads + sim) =================
__global__ __launch_bounds__(256) void dense75_kernel(
    const float* __restrict__ A0, const float* __restrict__ A1,
    const float* __restrict__ A2, const float* __restrict__ A3,
    const float* __restrict__ W0, const float* __restrict__ W1,
    const float* __restrict__ W2, const float* __restrict__ W3,
    const float* __restrict__ bb0, const float* __restrict__ bb1,
    const float* __restrict__ bb2, const float* __restrict__ bb3,
    float* __restrict__ o0, float* __restrict__ o1,
    float* __restrict__ o2, float* __restrict__ o3,
    const float* __restrict__ sw, const float* __restrict__ sb,
    float* __restrict__ simout){
  int slot = blockIdx.y;
  __shared__ float Ws[128*NC];
  __shared__ float bs[NC];
  if (slot < 4){
    const float* A = (slot==0)?A0:(slot==1)?A1:(slot==2)?A2:A3;
    const float* W = (slot==0)?W0:(slot==1)?W1:(slot==2)?W2:W3;
    const float* bb= (slot==0)?bb0:(slot==1)?bb1:(slot==2)?bb2:bb3;
    float* o       = (slot==0)?o0:(slot==1)?o1:(slot==2)?o2:o3;
    for (int i = threadIdx.x; i < 64*NC; i += 256) Ws[i] = W[i];
    if (threadIdx.x < NC) bs[threadIdx.x] = bb[threadIdx.x];
    __syncthreads();
    int row = blockIdx.x*256 + threadIdx.x;
    if (row >= NN) return;
    float acc[NC];
    #pragma unroll
    for (int n = 0; n < NC; ++n) acc[n] = bs[n];
    const float* a = A + (size_t)row*64;
    #pragma unroll 4
    for (int k = 0; k < 64; ++k){
      float av = fmaxf(a[k], 0.f);
      #pragma unroll
      for (int n = 0; n < NC; ++n) acc[n] += av*Ws[k*NC + n];
    }
    #pragma unroll
    for (int n = 0; n < NC; ++n) o[(size_t)row*NC + n] = acc[n];
  } else {
    for (int i = threadIdx.x; i < 128*NC; i += 256) Ws[i] = sw[i];
    if (threadIdx.x < NC) bs[threadIdx.x] = sb[threadIdx.x];
    __syncthreads();
    int row = blockIdx.x*256 + threadIdx.x;
    if (row >= NN) return;
    float acc[NC];
    #pragma unroll
    for (int n = 0; n < NC; ++n) acc[n] = bs[n];
    const float* a1 = A1 + (size_t)row*64;   // X2
    const float* a2 = A2 + (size_t)row*64;   // X3
    #pragma unroll 4
    for (int k = 0; k < 64; ++k){
      float av = a1[k];
      #pragma unroll
      for (int n = 0; n < NC; ++n) acc[n] += av*Ws[k*NC + n];
    }
    #pragma unroll 4
    for (int k = 0; k < 64; ++k){
      float av = a2[k];
      #pragma unroll
      for (int n = 0; n < NC; ++n) acc[n] += av*Ws[(64 + k)*NC + n];
    }
    #pragma unroll
    for (int n = 0; n < NC; ++n) simout[(size_t)row*NC + n] = acc[n];
  }
}

// ================= alpha / axpy =================
__global__ __launch_bounds__(1024) void alpha_kernel(const float* __restrict__ base, const float* __restrict__ gate,
                                                     const float* __restrict__ y, const int* __restrict__ index,
                                                     float* __restrict__ alpha_out){
  __shared__ float r1[1024], r2[1024];
  int tid = threadIdx.x;
  float s1 = 0.f, sall = 0.f;
  for (int i = tid; i < NIDX*NC; i += 1024){
    int ii = i / NC, n = i - ii*NC;
    int r = index[ii];
    float yv = y[(size_t)r*NC + n];
    float b = base[(size_t)r*NC + n];
    float g = gate[(size_t)r*NC + n];
    float te = expf(-b*yv);
    sall += te;
    if (g*yv >= 0.f) s1 += te;
  }
  r1[tid] = s1; r2[tid] = sall;
  __syncthreads();
  for (int off = 512; off > 0; off >>= 1){
    if (tid < off){ r1[tid] += r1[tid+off]; r2[tid] += r2[tid+off]; }
    __syncthreads();
  }
  if (tid == 0){
    float s2 = r2[0] - r1[0];
    alpha_out[0] = 0.5f*logf(s2/r1[0]);
  }
}

__global__ void axpy_kernel(const float* __restrict__ a, const float* __restrict__ b,
                            const float* __restrict__ alpha, float* __restrict__ out, int n){
  int i = blockIdx.x*blockDim.x + threadIdx.x;
  if (i < n) out[i] = a[i] + alpha[0]*b[i];
}

// ---------------- host ----------------
extern "C" void kernel_launch(void* const* d_in, const int* in_sizes, int n_in,
                              void* d_out, int out_size, void* d_ws, size_t ws_size,
                              hipStream_t stream){
  const float* x     = (const float*)d_in[0];
  const float* y     = (const float*)d_in[1];
  const int*   index = (const int*)d_in[2];
  const int*   a1r = (const int*)d_in[3];  const int* a1c = (const int*)d_in[4];  const float* a1v = (const float*)d_in[5];
  const int*   a3r = (const int*)d_in[9];  const int* a3c = (const int*)d_in[10]; const float* a3v = (const float*)d_in[11];
  const int*   a4r = (const int*)d_in[12]; const int* a4c = (const int*)d_in[13]; const float* a4v = (const float*)d_in[14];
  const int*   a5r = (const int*)d_in[15]; const int* a5c = (const int*)d_in[16]; const float* a5v = (const float*)d_in[17];
  const float* w1  = (const float*)d_in[18]; const float* b1  = (const float*)d_in[19];
  const float* w2  = (const float*)d_in[20]; const float* b2  = (const float*)d_in[21];
  const float* w3  = (const float*)d_in[22]; const float* b3  = (const float*)d_in[23];
  const float* w4  = (const float*)d_in[24]; const float* b4  = (const float*)d_in[25];
  const float* w5  = (const float*)d_in[26]; const float* b5  = (const float*)d_in[27];
  const float* w6  = (const float*)d_in[28]; const float* b6  = (const float*)d_in[29];
  const float* w10 = (const float*)d_in[30]; const float* b10 = (const float*)d_in[31];
  const float* w11 = (const float*)d_in[32]; const float* b11 = (const float*)d_in[33];
  const float* w12 = (const float*)d_in[34]; const float* b12 = (const float*)d_in[35];
  const float* d1w = (const float*)d_in[36]; const float* d1b = (const float*)d_in[37];
  const float* d2w = (const float*)d_in[38]; const float* d2b = (const float*)d_in[39];
  const float* d3w = (const float*)d_in[40]; const float* d3b = (const float*)d_in[41];
  const float* d4w = (const float*)d_in[42]; const float* d4b = (const float*)d_in[43];
  const float* sw  = (const float*)d_in[44]; const float* sb  = (const float*)d_in[45];
  float* out = (float*)d_out;
  (void)n_in; (void)in_sizes; (void)out_size; (void)ws_size;

  float* OUT_X2D = out;
  float* OUT_X3D = out + (size_t)NN*NC;
  float* OUT_P2  = out + (size_t)2*NN*NC;

  char* p = (char*)d_ws;
  auto carve = [&](size_t bytes) -> char* {
    char* q = p;
    p += (bytes + 255) & ~size_t(255);
    return q;
  };

  // Region A (102.5MB), time-shared: phase A: Xf (51.2MB)  phase B: H1_4 | SB_4 | H2_4
  const size_t XH_BYTES = (size_t)NB*NTK*4096*2;     // 51,249,152
  char* regionA = carve(2*XH_BYTES);
  unsigned short* Xf = (unsigned short*)regionA;
  __half* H1_4  = (__half*)regionA;                                  // 51.2MB
  __half* SB_4  = (__half*)(regionA + XH_BYTES);                     // 25.6MB
  __half* H2_4  = (__half*)(regionA + XH_BYTES + (size_t)4*NN*D2*2); // 25.6MB

  int2*  EINT4 = (int2*)carve((size_t)4*EE*8);
  __half* S1  = (__half*)carve((size_t)NN*D1*2);
  __half* S4  = (__half*)carve((size_t)NN*D1*2);
  __half* S10 = (__half*)carve((size_t)NN*D1*2);
  float* X1R  = (float*)carve((size_t)NN*D3*4);
  float* X2   = (float*)carve((size_t)NN*D3*4);
  float* X3   = (float*)carve((size_t)NN*D3*4);
  float* X4R  = (float*)carve((size_t)NN*D3*4);
  float* X1D  = (float*)carve((size_t)NN*NC*4);
  float* X4D  = (float*)carve((size_t)NN*NC*4);
  float* SIM  = (float*)carve((size_t)NN*NC*4);
  float* ALPHA= (float*)carve(256);
  int*   ROWP4 = (int*)carve((size_t)4*(NN+1)*4);
  int*   BCNTM = (int*)carve((size_t)4*NCHUNK*NBKT*4);
  int*   BLKOFF= (int*)carve((size_t)4*NCHUNK*NBKT*4);
  int*   BTOT  = (int*)carve((size_t)4*NBKT*4);
  int*   BBASE = (int*)carve((size_t)4*NBKT*4);
  const size_t BTE = (size_t)NTK*4096;
  unsigned short* B1H = (unsigned short*)carve(BTE*2); unsigned short* B1L = (unsigned short*)carve(BTE*2);
  unsigned short* B4H = (unsigned short*)carve(BTE*2); unsigned short* B4L = (unsigned short*)carve(BTE*2);
  unsigned short* B10H= (unsigned short*)carve(BTE*2); unsigned short* B10L= (unsigned short*)carve(BTE*2);
  unsigned short* V2H  = (unsigned short*)carve(4*2048*2); unsigned short* V2L  = (unsigned short*)carve(4*2048*2);
  unsigned short* V5H  = (unsigned short*)carve(4*2048*2); unsigned short* V5L  = (unsigned short*)carve(4*2048*2);
  unsigned short* V11H = (unsigned short*)carve(4*2048*2); unsigned short* V11L = (unsigned short*)carve(4*2048*2);
  unsigned short* V3H  = (unsigned short*)carve(2*2048*2); unsigned short* V3L  = (unsigned short*)carve(2*2048*2);
  unsigned short* V6H  = (unsigned short*)carve(2*2048*2); unsigned short* V6L  = (unsigned short*)carve(2*2048*2);
  unsigned short* V12H = (unsigned short*)carve(2*2048*2); unsigned short* V12L = (unsigned short*)carve(2*2048*2);
  unsigned* ECVP4 = (unsigned*)carve((size_t)4*EE*4);

  __half* H1s[4]; __half* SBs[4]; __half* H2s[4];
  for (int s = 0; s < 4; ++s){
    H1s[s] = H1_4 + (size_t)s*NN*D1;
    SBs[s] = SB_4 + (size_t)s*NN*D2;
    H2s[s] = H2_4 + (size_t)s*NN*D2;
  }

  // ---- phase A: convx(fp16) ∥ weight prep ∥ bchist (slots: 0=a5, 1=a4, 2=a3, 3=a1) ----
  megaA_kernel<<<NCVX + 48 + 18 + 4*NCHUNK, 256, 0, stream>>>(
      x, Xf,
      w1, w4, w10, B1H,B1L, B4H,B4L, B10H,B10L,
      w2, w5, w11, V2H,V2L, V5H,V5L, V11H,V11L,
      w3, w6, w12, V3H,V3L, V6H,V6L, V12H,V12L,
      a5r, a4r, a3r, a1r, BCNTM);
  // ---- phase B: scans ----
  bscan_kernel<<<dim3(NBKT,4), 256, 0, stream>>>(BCNTM, BLKOFF, BTOT);
  bbase_kernel<<<4, 256, 0, stream>>>(BTOT, BBASE);
  // ---- phase C: gemm3f(fp16 A) ∥ bin4 ----
  megaC_kernel<<<3*NB + 4*NCHUNK, 256, 0, stream>>>(
      Xf, B1H,B1L, B4H,B4L, B10H,B10L, S1, S4, S10,
      a5r,a5c,a5v, a4r,a4c,a4v, a3r,a3c,a3v, a1r,a1c,a1v,
      BBASE, BLKOFF, EINT4);
  // ---- phase D: order4 (writes ROWP4); Xf dead after megaC -> regionA reused ----
  order4_kernel<<<dim3(NBKT,4), 256, 0, stream>>>(BBASE, BTOT, EINT4, ECVP4, ROWP4);

  // ---- branch stages ----
  spmm4_kernel<128,1,__half><<<4*NBLK4, 256, 0, stream>>>(
      ROWP4, ECVP4, S1,S4,S4,S10, b1,b4,b4,b10, H1s[0],H1s[1],H1s[2],H1s[3]);
  mfma4f_kernel<<<dim3(NB,4), 256, 0, stream>>>(
      H1s[0],H1s[1],H1s[2],H1s[3], V2H,V5H,V5H,V11H, V2L,V5L,V5L,V11L,
      SBs[0],SBs[1],SBs[2],SBs[3], NN, D1);
  spmm4_kernel<64,1,__half><<<4*NBLK4, 256, 0, stream>>>(
      ROWP4, ECVP4, SBs[0],SBs[1],SBs[2],SBs[3], b2,b5,b5,b11, H2s[0],H2s[1],H2s[2],H2s[3]);
  mfma4f_kernel<<<dim3(NB,4), 256, 0, stream>>>(
      H2s[0],H2s[1],H2s[2],H2s[3], V3H,V6H,V6H,V12H, V3L,V6L,V6L,V12L,
      SBs[0],SBs[1],SBs[2],SBs[3], NN, D2);
  spmm4_kernel<64,0,float><<<4*NBLK4, 256, 0, stream>>>(
      ROWP4, ECVP4, SBs[0],SBs[1],SBs[2],SBs[3], b3,b6,b6,b12, X1R,X2,X3,X4R);
  dense75_kernel<<<dim3((NN+255)/256,5), 256, 0, stream>>>(
      X1R,X2,X3,X4R, d1w,d2w,d3w,d4w, d1b,d2b,d3b,d4b,
      X1D, OUT_X2D, OUT_X3D, X4D, sw, sb, SIM);

  // ---- adaboost epilogue ----
  alpha_kernel<<<1, 1024, 0, stream>>>(X4D, SIM, y, index, ALPHA);
  axpy_kernel<<<((NN*NC)+255)/256, 256, 0, stream>>>(X4D, SIM, ALPHA, OUT_P2, NN*NC);
  alpha_kernel<<<1, 1024, 0, stream>>>(OUT_P2, X1D, y, index, ALPHA+1);
  axpy_kernel<<<((NN*NC)+255)/256, 256, 0, stream>>>(OUT_P2, X1D, ALPHA+1, OUT_P2, NN*NC);
}